// Round 1
// baseline (87.292 us; speedup 1.0000x reference)
//
#include <hip/hip_runtime.h>
#include <stdint.h>

// MetalQuantizedLinear: out[16,8192] = x[16,8192] @ dequant(W_packed[1024,8192], scales[64,8192])
//   w[k][n] = ((nibble_{k%8} of wp[k/8][n]) - 8) * 0.5 * scales[k/128][n]
//
// DTYPE (verified r4/r5, passing): x/scales/out are FLOAT32 on device.
// HARNESS: ws_size ~= 268 MB (43us poison fill dominates top-5, harness-fixed);
// improvable budget = dur_us - fill ~= 39us of kernel+launch work.
//
// r7 change: OCCUPANCY 2x. r6 ran 256 blocks x 512 thr = 1 block/CU = 2 waves/SIMD;
// a ~6us-roofline memory-bound gemm left at 2 waves/SIMD is latency-exposed (every
// vmcnt bubble in the 8-group pipeline stalls the SIMD; no co-resident block fills
// the gap). r7: 512 blocks x 512 thr, 16 cols/block (ONE mfma tile, dword weight
// loads, 64B/quad segments), __launch_bounds__(512,4) caps VGPR<=128 so 2 blocks/CU
// are resident -> 16 waves/CU = 4/SIMD. Weight traffic unchanged (64 KB/block, read
// once). A-traffic doubles to 128 MB but xp (256 KB) is L2-resident per XCD.
//
// Gemm math identical to r6 (passing): wave wv owns k-eighth [wv*1024,+1024) = 8
// groups; lane owns col n0+c. mfma_f32_16x16x32_f16: A = fp16(x) exact (prepacked
// pairs (x[+r], x[+r+4])); B = (nib-8) exact via (0x6400|nib)-1032. 0.5*scale per
// group in f32 on C. 8-wave LDS k-reduction; wave 0 rounds through fp16 (RNE).

typedef _Float16 half8  __attribute__((ext_vector_type(8)));
typedef _Float16 half2v __attribute__((ext_vector_type(2)));
typedef float    floatx4 __attribute__((ext_vector_type(4)));

constexpr int Kdim = 8192;
constexpr int Ndim = 8192;

// ---------------------------------------------------------------------------
// Prepack: xp[sq] (16B, sq = m + 16*(k/8)) holds fp16 pairs (x[m][8s+r], x[m][8s+r+4]).
// Linear write xp[tid]; read is 16-row scattered but runs once (16K threads).
// ---------------------------------------------------------------------------
__global__ void prepack_a(const float* __restrict__ x, uint4* __restrict__ xp) {
    int tid = blockIdx.x * 256 + threadIdx.x;   // 0..16383
    int m  = tid & 15;
    int sq = tid >> 4;                          // k-octet index 0..1023
    const float4* x4 = reinterpret_cast<const float4*>(x);
    float4 lo = x4[(size_t)m * (Kdim / 4) + sq * 2];      // k 8sq+0..3
    float4 hi = x4[(size_t)m * (Kdim / 4) + sq * 2 + 1];  // k 8sq+4..7
    uint4 o;
    o.x = __builtin_bit_cast(uint32_t, __builtin_amdgcn_cvt_pkrtz(lo.x, hi.x));
    o.y = __builtin_bit_cast(uint32_t, __builtin_amdgcn_cvt_pkrtz(lo.y, hi.y));
    o.z = __builtin_bit_cast(uint32_t, __builtin_amdgcn_cvt_pkrtz(lo.z, hi.z));
    o.w = __builtin_bit_cast(uint32_t, __builtin_amdgcn_cvt_pkrtz(lo.w, hi.w));
    xp[tid] = o;   // xp index sq*16 + m == tid  (coalesced)
}

__global__ __launch_bounds__(512, 4) void fused_fp4_gemm(
        const uint4* __restrict__ xp,
        const uint32_t* __restrict__ wp,
        const float* __restrict__ scales,
        float* __restrict__ out) {
    __shared__ float red[8][64][4];   // 8 KB: per-wave partial C frags

    const int t    = threadIdx.x;
    const int wv   = t >> 6;      // k-eighth 0..7
    const int lane = t & 63;
    const int c    = lane & 15;   // A row m; col index
    const int q    = lane >> 4;   // quad -> k-subblock / C row group
    const int nb   = blockIdx.x;  // 0..511
    const int n0   = nb * 16 + c; // absolute column this lane owns

    // Weight word for K-step s (=4g+tt): word-row wv*128 + 4s + q, col n0.
    const uint32_t* wrow = wp + (size_t)(wv * 128 + q) * Ndim + n0;
    // A frags: xp[(wv*128 + 4s + q)*16 + c] = xp[wv*2048 + s*64 + lane]. Linear!
    const uint4* abase = xp + wv * 2048 + lane;
    // Scale for group g: scales[wv*8 + g][n0].
    const float* srow = scales + (size_t)(wv * 8) * Ndim + n0;

    uint32_t wbuf[4][4];    // rolling: 4 groups of weights in flight (3 ahead)
    uint4    abuf[2][4];    // rolling: 2 groups of A frags
    float    scbuf[3];      // rolling: scales 2 ahead

#pragma unroll
    for (int g0 = 0; g0 < 3; ++g0)
#pragma unroll
        for (int tt = 0; tt < 4; ++tt)
            wbuf[g0][tt] = wrow[(size_t)(16 * g0 + 4 * tt) * Ndim];
#pragma unroll
    for (int tt = 0; tt < 4; ++tt) abuf[0][tt] = abase[tt * 64];
    scbuf[0] = srow[0];
    scbuf[1] = srow[(size_t)Ndim];

    floatx4 accm = {0.f, 0.f, 0.f, 0.f};

#pragma unroll
    for (int g = 0; g < 8; ++g) {
        const int gw = (g + 3 < 8) ? g + 3 : 7;   // clamped prefetch (dup = cache hit)
#pragma unroll
        for (int tt = 0; tt < 4; ++tt)
            wbuf[(g + 3) & 3][tt] = wrow[(size_t)(16 * gw + 4 * tt) * Ndim];
        const int ga = (g + 1 < 8) ? g + 1 : 7;
#pragma unroll
        for (int tt = 0; tt < 4; ++tt)
            abuf[(g + 1) & 1][tt] = abase[(4 * ga + tt) * 64];
        const int gs = (g + 2 < 8) ? g + 2 : 7;
        scbuf[(g + 2) % 3] = srow[(size_t)gs * Ndim];

        floatx4 accg = {0.f, 0.f, 0.f, 0.f};
#pragma unroll
        for (int tt = 0; tt < 4; ++tt) {
            half8 af = __builtin_bit_cast(half8, abuf[g & 1][tt]);
            // B frag reg r = fp16 pair (nib_r-8, nib_{r+4}-8), exact:
            // 0x6400|nib = 1024+nib; subtract 1032.
            const uint32_t w = wbuf[g & 3][tt];
            const half2v koff = {(_Float16)1032.0f, (_Float16)1032.0f};
            union { uint32_t u[4]; half8 h; } bf;
#pragma unroll
            for (int r = 0; r < 4; ++r) {
                uint32_t mm = ((w >> (4 * r)) & 0x000F000Fu) | 0x64006400u;
                bf.u[r] = __builtin_bit_cast(uint32_t, __builtin_bit_cast(half2v, mm) - koff);
            }
            accg = __builtin_amdgcn_mfma_f32_16x16x32_f16(af, bf.h, accg, 0, 0, 0);
        }
        const float sc = scbuf[g % 3];
#pragma unroll
        for (int r = 0; r < 4; ++r)
            accm[r] = fmaf(0.5f * sc, accg[r], accm[r]);
    }

    // Cross-wave k-reduction via LDS.
    *reinterpret_cast<float4*>(&red[wv][lane][0]) =
        make_float4(accm[0], accm[1], accm[2], accm[3]);
    __syncthreads();

    if (wv == 0) {
        float v[4] = {0.f, 0.f, 0.f, 0.f};
#pragma unroll
        for (int s = 0; s < 8; ++s) {
            float4 p = *reinterpret_cast<const float4*>(&red[s][lane][0]);
            v[0] += p.x; v[1] += p.y; v[2] += p.z; v[3] += p.w;
        }
        // C/D layout (verified): col = lane&15 -> global col n0; row = q*4+r.
        // Round through fp16 (RNE) to match reference's astype(float16).
#pragma unroll
        for (int r = 0; r < 4; ++r)
            out[(size_t)(q * 4 + r) * Ndim + n0] = (float)(_Float16)v[r];
    }
}

extern "C" void kernel_launch(void* const* d_in, const int* in_sizes, int n_in,
                              void* d_out, int out_size, void* d_ws, size_t ws_size,
                              hipStream_t stream) {
    const float*    xx     = (const float*)d_in[0];
    const uint32_t* wpk    = (const uint32_t*)d_in[1];
    const float*    scales = (const float*)d_in[2];
    float*          outp   = (float*)d_out;
    uint4*          xp     = (uint4*)d_ws;   // 256 KB of the ~268 MB workspace

    prepack_a<<<64, 256, 0, stream>>>(xx, xp);
    fused_fp4_gemm<<<512, 512, 0, stream>>>(xp, wpk, scales, outp);
}

// Round 2
// 82.553 us; speedup vs baseline: 1.0574x; 1.0574x over previous
//
#include <hip/hip_runtime.h>
#include <stdint.h>

// MetalQuantizedLinear: out[16,8192] = x[16,8192] @ dequant(W_packed[1024,8192], scales[64,8192])
//   w[k][n] = ((nibble_{k%8} of wp[k/8][n]) - 8) * 0.5 * scales[k/128][n]
//
// DTYPE (verified r4/r5, passing): x/scales/out are FLOAT32 on device.
// HARNESS: ws_size ~= 268 MB (43us poison fill dominates top-5, harness-fixed);
// dur_us carries ~55-85us of fixed harness work; kernel share ~8us (32MB weight
// stream @ 6.3 TB/s = 5.1us floor + prepack + launches).
//
// r8 = REVERT to r6 (83.0us, best verified) + dead-prefetch elimination.
// r7 (512 blocks x 16 cols, 2 blocks/CU) REGRESSED to 87.3us -> gemm is NOT
// latency-bound at 2 waves/SIMD; r7 traded away 128B/quad weight coalescing and
// blew the per-XCD L2 working set for xp (16MB/XCD vs 4MB L2). Reverted.
// r8 micro-fix: clamped prefetches (gw/ga/gs -> 7) re-issued ~12 dup dwordx2 +
// 4 dwordx4 + 2 dword loads per wave in the last groups; g is compile-time in the
// unrolled loop so `if (g+3<8)` guards fold statically and delete them. Slot trace
// verified: groups 5/6/7 remain live in wbuf slots 1/2/3, abuf slot 1, scbuf 1/0.
//
// Gemm (structure verified r5): grid 256 x 512 (8 waves). Block = 32 cols; wave
// wv owns k-eighth [wv*1024,+1024) = 8 groups. Lane owns cols n0, n0+1 (uint2
// weight loads -> 128B/quad). mfma_f32_16x16x32_f16: A = fp16(x) exact, pairs
// (x[+r], x[+r+4]); B = (nib-8) exact via (0x6400|nib)-1032. 0.5*scale per group
// in f32 on C. 8-wave LDS k-reduction; waves 0/1 round through fp16 (RNE) to f32.

typedef _Float16 half8  __attribute__((ext_vector_type(8)));
typedef _Float16 half2v __attribute__((ext_vector_type(2)));
typedef float    floatx4 __attribute__((ext_vector_type(4)));

constexpr int Kdim = 8192;
constexpr int Ndim = 8192;

// ---------------------------------------------------------------------------
// Prepack: xp[sq] (16B, sq = m + 16*(k/8)) holds fp16 pairs (x[m][8s+r], x[m][8s+r+4]).
// Linear write xp[tid]; read is 16-row scattered but runs once (16K threads).
// ---------------------------------------------------------------------------
__global__ void prepack_a(const float* __restrict__ x, uint4* __restrict__ xp) {
    int tid = blockIdx.x * 256 + threadIdx.x;   // 0..16383
    int m  = tid & 15;
    int sq = tid >> 4;                          // k-octet index 0..1023
    const float4* x4 = reinterpret_cast<const float4*>(x);
    float4 lo = x4[(size_t)m * (Kdim / 4) + sq * 2];      // k 8sq+0..3
    float4 hi = x4[(size_t)m * (Kdim / 4) + sq * 2 + 1];  // k 8sq+4..7
    uint4 o;
    o.x = __builtin_bit_cast(uint32_t, __builtin_amdgcn_cvt_pkrtz(lo.x, hi.x));
    o.y = __builtin_bit_cast(uint32_t, __builtin_amdgcn_cvt_pkrtz(lo.y, hi.y));
    o.z = __builtin_bit_cast(uint32_t, __builtin_amdgcn_cvt_pkrtz(lo.z, hi.z));
    o.w = __builtin_bit_cast(uint32_t, __builtin_amdgcn_cvt_pkrtz(lo.w, hi.w));
    xp[tid] = o;   // xp index sq*16 + m == tid  (coalesced)
}

__global__ __launch_bounds__(512, 2) void fused_fp4_gemm(
        const uint4* __restrict__ xp,
        const uint32_t* __restrict__ wp,
        const float* __restrict__ scales,
        float* __restrict__ out) {
    __shared__ float red[8][2][64][4];   // 16 KB: per-wave partial C frags, 2 tiles

    const int t    = threadIdx.x;
    const int wv   = t >> 6;      // k-eighth 0..7
    const int lane = t & 63;
    const int c    = lane & 15;   // A row m; col pair index
    const int q    = lane >> 4;   // quad -> k-subblock / C row group
    const int nb   = blockIdx.x;  // 0..255
    const int n0   = nb * 32 + 2 * c;   // tile0 col; tile1 col = n0+1

    // Weight words for K-step s (=4g+tt): word-row wv*128 + 4s + q, cols (n0,n0+1).
    const uint2* wrow = reinterpret_cast<const uint2*>(wp) + ((size_t)(wv * 128 + q) * Ndim + n0) / 2;
    // A frags: xp[(wv*128 + 4s + q)*16 + c] = xp[wv*2048 + s*64 + lane]. Linear!
    const uint4* abase = xp + wv * 2048 + lane;
    // Scales for group g: scales[wv*8 + g][n0, n0+1].
    const float2* srow = reinterpret_cast<const float2*>(scales) + ((size_t)(wv * 8) * Ndim + n0) / 2;

    uint2  wbuf[4][4];      // rolling: 4 groups of weights in flight (3 ahead)
    uint4  abuf[2][4];      // rolling: 2 groups of A frags
    float2 scbuf[3];        // rolling: scales 2 ahead

#pragma unroll
    for (int g0 = 0; g0 < 3; ++g0)
#pragma unroll
        for (int tt = 0; tt < 4; ++tt)
            wbuf[g0][tt] = wrow[(size_t)(16 * g0 + 4 * tt) * (Ndim / 2)];
#pragma unroll
    for (int tt = 0; tt < 4; ++tt) abuf[0][tt] = abase[tt * 64];
    scbuf[0] = srow[0];
    scbuf[1] = srow[(size_t)(Ndim / 2)];

    floatx4 accm0 = {0.f, 0.f, 0.f, 0.f};
    floatx4 accm1 = {0.f, 0.f, 0.f, 0.f};

#pragma unroll
    for (int g = 0; g < 8; ++g) {
        // Prefetches: g is compile-time (unrolled), guards fold; no dup re-loads
        // for the tail groups (slot liveness verified, see header).
        if (g + 3 < 8) {
#pragma unroll
            for (int tt = 0; tt < 4; ++tt)
                wbuf[(g + 3) & 3][tt] = wrow[(size_t)(16 * (g + 3) + 4 * tt) * (Ndim / 2)];
        }
        if (g + 1 < 8) {
#pragma unroll
            for (int tt = 0; tt < 4; ++tt)
                abuf[(g + 1) & 1][tt] = abase[(4 * (g + 1) + tt) * 64];
        }
        if (g + 2 < 8)
            scbuf[(g + 2) % 3] = srow[(size_t)(g + 2) * (Ndim / 2)];

        floatx4 accg0 = {0.f, 0.f, 0.f, 0.f};
        floatx4 accg1 = {0.f, 0.f, 0.f, 0.f};
#pragma unroll
        for (int tt = 0; tt < 4; ++tt) {
            half8 af = __builtin_bit_cast(half8, abuf[g & 1][tt]);
            // B frag reg r = fp16 pair (nib_r-8, nib_{r+4}-8), exact:
            // 0x6400|nib = 1024+nib; subtract 1032.
            const uint2 w = wbuf[g & 3][tt];
            const half2v koff = {(_Float16)1032.0f, (_Float16)1032.0f};
            union { uint32_t u[4]; half8 h; } bf0, bf1;
#pragma unroll
            for (int r = 0; r < 4; ++r) {
                uint32_t m0 = ((w.x >> (4 * r)) & 0x000F000Fu) | 0x64006400u;
                uint32_t m1 = ((w.y >> (4 * r)) & 0x000F000Fu) | 0x64006400u;
                bf0.u[r] = __builtin_bit_cast(uint32_t, __builtin_bit_cast(half2v, m0) - koff);
                bf1.u[r] = __builtin_bit_cast(uint32_t, __builtin_bit_cast(half2v, m1) - koff);
            }
            accg0 = __builtin_amdgcn_mfma_f32_16x16x32_f16(af, bf0.h, accg0, 0, 0, 0);
            accg1 = __builtin_amdgcn_mfma_f32_16x16x32_f16(af, bf1.h, accg1, 0, 0, 0);
        }
        const float2 sc = scbuf[g % 3];
#pragma unroll
        for (int r = 0; r < 4; ++r) {
            accm0[r] = fmaf(0.5f * sc.x, accg0[r], accm0[r]);
            accm1[r] = fmaf(0.5f * sc.y, accg1[r], accm1[r]);
        }
    }

    // Cross-wave k-reduction via LDS.
    *reinterpret_cast<float4*>(&red[wv][0][lane][0]) =
        make_float4(accm0[0], accm0[1], accm0[2], accm0[3]);
    *reinterpret_cast<float4*>(&red[wv][1][lane][0]) =
        make_float4(accm1[0], accm1[1], accm1[2], accm1[3]);
    __syncthreads();

    if (wv < 2) {   // wave wv reduces tile wv
        float v[4] = {0.f, 0.f, 0.f, 0.f};
#pragma unroll
        for (int s = 0; s < 8; ++s) {
            float4 p = *reinterpret_cast<const float4*>(&red[s][wv][lane][0]);
            v[0] += p.x; v[1] += p.y; v[2] += p.z; v[3] += p.w;
        }
        // C/D layout (verified): col = lane&15 -> global col n0+wv; row = q*4+r.
        // Round through fp16 (RNE) to match reference's astype(float16).
#pragma unroll
        for (int r = 0; r < 4; ++r)
            out[(size_t)(q * 4 + r) * Ndim + n0 + wv] = (float)(_Float16)v[r];
    }
}

extern "C" void kernel_launch(void* const* d_in, const int* in_sizes, int n_in,
                              void* d_out, int out_size, void* d_ws, size_t ws_size,
                              hipStream_t stream) {
    const float*    xx     = (const float*)d_in[0];
    const uint32_t* wpk    = (const uint32_t*)d_in[1];
    const float*    scales = (const float*)d_in[2];
    float*          outp   = (float*)d_out;
    uint4*          xp     = (uint4*)d_ws;   // 256 KB of the ~268 MB workspace

    prepack_a<<<64, 256, 0, stream>>>(xx, xp);
    fused_fp4_gemm<<<256, 512, 0, stream>>>(xp, wpk, scales, outp);
}